// Round 1
// baseline (715.689 us; speedup 1.0000x reference)
//
#include <hip/hip_runtime.h>
#include <hip/hip_bf16.h>
#include <math.h>

// Problem constants
#define B_  64
#define T_  2048
#define DEC_ 1024
#define ENC_ 512
#define ATT_ 128
#define LOC_ 32
#define KW_  31

// ---------------------------------------------------------------------------
// K1: prep — q = query @ Q_w.T + Q_b ; eff[k][a] = sum_c loc_proj[a,c]*conv_w[c,k]
//      ; vwt[e][a] = V_w[a][e]  (transpose so GEMM staging is contiguous)
// grid: 64 (q) + 1 (eff) + 32 (transpose) = 97 blocks x 256
// ---------------------------------------------------------------------------
__global__ __launch_bounds__(256) void prep_kernel(
    const float* __restrict__ query, const float* __restrict__ Q_w,
    const float* __restrict__ Q_b, const float* __restrict__ conv_w,
    const float* __restrict__ loc_proj_w, const float* __restrict__ V_w,
    float* __restrict__ qbuf, float* __restrict__ effw, float* __restrict__ vwt)
{
    int bi = blockIdx.x, tid = threadIdx.x;
    if (bi < B_) {
        __shared__ float sq[DEC_];
        for (int i = tid; i < DEC_; i += 256) sq[i] = query[bi * DEC_ + i];
        __syncthreads();
        if (tid < ATT_) {
            float acc = Q_b[tid];
            const float* qw = Q_w + (size_t)tid * DEC_;
            for (int k = 0; k < DEC_; ++k) acc += sq[k] * qw[k];
            qbuf[bi * ATT_ + tid] = acc;
        }
    } else if (bi == B_) {
        if (tid < ATT_) {
            int a = tid;
            for (int k = 0; k < KW_; ++k) {
                float s = 0.f;
                for (int c = 0; c < LOC_; ++c)
                    s += loc_proj_w[a * LOC_ + c] * conv_w[c * KW_ + k];
                effw[k * ATT_ + a] = s;   // [k][a] layout
            }
        }
    } else {
        int idx0 = (bi - B_ - 1) * 2048;
        #pragma unroll
        for (int j = 0; j < 8; ++j) {
            int idx = idx0 + j * 256 + tid;      // idx = e*128 + a
            int e = idx >> 7, a = idx & 127;
            vwt[idx] = V_w[a * ENC_ + e];
        }
    }
}

// ---------------------------------------------------------------------------
// K2: energies[b,t] = sum_a v_w[a]*tanh(q[b,a] + vcache[b,t,a] + loc[b,t,a])
// Block: 64 t x 128 a tile, ENC accumulated in 8 chunks of 64 via LDS.
// Thread: 4t x 8a register tile -> 128 FMA per 12 ds_read_b128.
// grid (T/64=32, B) = 2048 blocks x 256
// ---------------------------------------------------------------------------
#define TT 64
#define KC 64
__global__ __launch_bounds__(256) void energy_kernel(
    const float* __restrict__ values, const float* __restrict__ cum,
    const float* __restrict__ qbuf, const float* __restrict__ effw,
    const float* __restrict__ vwt, const float* __restrict__ vw,
    float* __restrict__ energies)
{
    __shared__ float sA[TT][68];       // values chunk [t][e], pad 4 -> conflict-free reads
    __shared__ float sB[KC][ATT_];     // V_wT chunk [e][a]; reused for eff in epilogue
    __shared__ float sx[TT + 32];      // cum window [t0-15 .. t0+78]

    const int tid = threadIdx.x;
    const int t0 = blockIdx.x * TT;
    const int b  = blockIdx.y;

    if (tid < TT + 30) {
        int g = t0 - 15 + tid;
        sx[tid] = (g >= 0 && g < T_) ? cum[b * T_ + g] : 0.f;
    }

    const int tt  = tid >> 4;          // 0..15
    const int aa  = tid & 15;          // 0..15
    const int t0s = tt * 4;
    const int a0s = aa * 8;

    float acc[4][8];
    #pragma unroll
    for (int i = 0; i < 4; ++i)
        #pragma unroll
        for (int j = 0; j < 8; ++j) acc[i][j] = 0.f;

    const float* vptr = values + ((size_t)b * T_ + t0) * ENC_;

    for (int kc = 0; kc < ENC_; kc += KC) {
        __syncthreads();
        // stage sA: 64t x 64e = 1024 float4, 4 per thread (coalesced)
        #pragma unroll
        for (int p = 0; p < 4; ++p) {
            int fi = p * 256 + tid;
            int t = fi >> 4, e4 = (fi & 15) * 4;
            float4 v = *(const float4*)(vptr + (size_t)t * ENC_ + kc + e4);
            *(float4*)(&sA[t][e4]) = v;
        }
        // stage sB: 64e x 128a = 2048 float4, 8 per thread (contiguous copy)
        #pragma unroll
        for (int p = 0; p < 8; ++p) {
            int fi = p * 256 + tid;
            int k = fi >> 5, a4 = (fi & 31) * 4;
            *(float4*)(&sB[k][a4]) = *(const float4*)(vwt + (size_t)(kc + k) * ATT_ + a4);
        }
        __syncthreads();
        #pragma unroll
        for (int k4 = 0; k4 < KC / 4; ++k4) {
            float4 af[4];
            float4 bf[4][2];
            #pragma unroll
            for (int i = 0; i < 4; ++i)
                af[i] = *(const float4*)(&sA[t0s + i][k4 * 4]);
            #pragma unroll
            for (int j = 0; j < 4; ++j) {
                bf[j][0] = *(const float4*)(&sB[k4 * 4 + j][a0s]);
                bf[j][1] = *(const float4*)(&sB[k4 * 4 + j][a0s + 4]);
            }
            #pragma unroll
            for (int j = 0; j < 4; ++j) {          // k substep
                #pragma unroll
                for (int i = 0; i < 4; ++i) {      // t
                    float av = ((const float*)&af[i])[j];
                    acc[i][0] += av * bf[j][0].x;
                    acc[i][1] += av * bf[j][0].y;
                    acc[i][2] += av * bf[j][0].z;
                    acc[i][3] += av * bf[j][0].w;
                    acc[i][4] += av * bf[j][1].x;
                    acc[i][5] += av * bf[j][1].y;
                    acc[i][6] += av * bf[j][1].z;
                    acc[i][7] += av * bf[j][1].w;
                }
            }
        }
    }

    // ---- epilogue: loc conv (fold into acc), + q, tanh, dot v_w ----
    __syncthreads();
    float* seff = &sB[0][0];                 // 31*128 = 3968 floats <= 8192
    for (int i = tid; i < KW_ * ATT_; i += 256) seff[i] = effw[i];
    __syncthreads();

    // loc[t][a] = sum_k eff[k][a] * x[t0 + t + k - 15]  (sx[0] == t0-15)
    for (int k = 0; k < KW_; ++k) {
        float xv[4];
        #pragma unroll
        for (int i = 0; i < 4; ++i) xv[i] = sx[t0s + i + k];
        float ef[8];
        #pragma unroll
        for (int j = 0; j < 8; ++j) ef[j] = seff[k * ATT_ + a0s + j];
        #pragma unroll
        for (int i = 0; i < 4; ++i)
            #pragma unroll
            for (int j = 0; j < 8; ++j) acc[i][j] += xv[i] * ef[j];
    }

    float qv[8], vv[8];
    #pragma unroll
    for (int j = 0; j < 8; ++j) {
        qv[j] = qbuf[b * ATT_ + a0s + j];
        vv[j] = vw[a0s + j];
    }

    float part[4] = {0.f, 0.f, 0.f, 0.f};
    #pragma unroll
    for (int i = 0; i < 4; ++i)
        #pragma unroll
        for (int j = 0; j < 8; ++j) {
            float z = qv[j] + acc[i][j];
            part[i] += vv[j] * tanhf(z);
        }

    // reduce across the 16 aa-lanes (consecutive lanes within the wave)
    #pragma unroll
    for (int m = 8; m >= 1; m >>= 1) {
        #pragma unroll
        for (int i = 0; i < 4; ++i)
            part[i] += __shfl_xor(part[i], m, 64);
    }
    if (aa == 0) {
        #pragma unroll
        for (int i = 0; i < 4; ++i)
            energies[b * T_ + t0 + t0s + i] = part[i];
    }
}

// ---------------------------------------------------------------------------
// K3: softmax over T per b; also zero the context output region for K4 atomics.
// grid B x 256
// ---------------------------------------------------------------------------
__global__ __launch_bounds__(256) void softmax_kernel(
    const float* __restrict__ energies, const unsigned char* __restrict__ mask,
    float* __restrict__ out)
{
    int b = blockIdx.x, tid = threadIdx.x;
    float* ctx  = out;                 // B*ENC
    float* wout = out + B_ * ENC_;     // B*T

    for (int i = tid; i < ENC_; i += 256) ctx[b * ENC_ + i] = 0.f;

    float e[8];
    float mx = -INFINITY;
    #pragma unroll
    for (int p = 0; p < 8; ++p) {
        int t = p * 256 + tid;
        float v = energies[b * T_ + t];
        if (mask[b * T_ + t]) v = -INFINITY;
        e[p] = v;
        mx = fmaxf(mx, v);
    }
    #pragma unroll
    for (int m = 32; m >= 1; m >>= 1) mx = fmaxf(mx, __shfl_xor(mx, m, 64));
    __shared__ float red[8];
    int wave = tid >> 6;
    if ((tid & 63) == 0) red[wave] = mx;
    __syncthreads();
    mx = fmaxf(fmaxf(red[0], red[1]), fmaxf(red[2], red[3]));

    float sum = 0.f;
    #pragma unroll
    for (int p = 0; p < 8; ++p) {
        e[p] = expf(e[p] - mx);
        sum += e[p];
    }
    #pragma unroll
    for (int m = 32; m >= 1; m >>= 1) sum += __shfl_xor(sum, m, 64);
    if ((tid & 63) == 0) red[4 + wave] = sum;
    __syncthreads();
    sum = red[4] + red[5] + red[6] + red[7];
    float inv = 1.f / sum;
    #pragma unroll
    for (int p = 0; p < 8; ++p)
        wout[b * T_ + p * 256 + tid] = e[p] * inv;
}

// ---------------------------------------------------------------------------
// K4: context[b,e] = sum_t w[b,t] * values[b,t,e]
// grid (B*8) blocks; each block does a 256-t segment, full 512 e (float4),
// atomicAdd into zeroed ctx.
// ---------------------------------------------------------------------------
__global__ __launch_bounds__(256) void context_kernel(
    const float* __restrict__ values, const float* __restrict__ w,
    float* __restrict__ ctx)
{
    int bs = blockIdx.x;
    int b = bs >> 3, seg = bs & 7;
    int tid = threadIdx.x;
    int tt = tid >> 7;                 // 0..1
    int e4 = (tid & 127) * 4;          // 0..508

    __shared__ float sw[256];
    int tbase = seg * 256;
    sw[tid] = w[b * T_ + tbase + tid];
    __syncthreads();

    float4 acc = make_float4(0.f, 0.f, 0.f, 0.f);
    const float* vp = values + ((size_t)b * T_ + tbase) * ENC_ + e4;
    #pragma unroll 4
    for (int t = tt; t < 256; t += 2) {
        float4 v = *(const float4*)(vp + (size_t)t * ENC_);
        float wv = sw[t];
        acc.x += wv * v.x; acc.y += wv * v.y;
        acc.z += wv * v.z; acc.w += wv * v.w;
    }

    __shared__ float red[512];
    if (tt == 1) *(float4*)&red[e4] = acc;
    __syncthreads();
    if (tt == 0) {
        float4 o = *(const float4*)&red[e4];
        atomicAdd(&ctx[b * ENC_ + e4 + 0], acc.x + o.x);
        atomicAdd(&ctx[b * ENC_ + e4 + 1], acc.y + o.y);
        atomicAdd(&ctx[b * ENC_ + e4 + 2], acc.z + o.z);
        atomicAdd(&ctx[b * ENC_ + e4 + 3], acc.w + o.w);
    }
}

// ---------------------------------------------------------------------------
extern "C" void kernel_launch(void* const* d_in, const int* in_sizes, int n_in,
                              void* d_out, int out_size, void* d_ws, size_t ws_size,
                              hipStream_t stream) {
    const float* query       = (const float*)d_in[0];
    const float* values      = (const float*)d_in[1];
    const float* cum         = (const float*)d_in[2];
    const unsigned char* mask= (const unsigned char*)d_in[3];
    const float* Q_w         = (const float*)d_in[4];
    const float* Q_b         = (const float*)d_in[5];
    const float* V_w         = (const float*)d_in[6];
    const float* conv_w      = (const float*)d_in[7];
    const float* loc_proj_w  = (const float*)d_in[8];
    const float* v_w         = (const float*)d_in[9];

    float* out = (float*)d_out;
    float* ws  = (float*)d_ws;
    // ws layout (floats): qbuf[8192] | effw[4096] | vwt[65536] | energies[131072]
    float* qbuf     = ws;
    float* effw     = ws + 8192;
    float* vwt      = ws + 12288;
    float* energies = ws + 77824;

    prep_kernel<<<97, 256, 0, stream>>>(query, Q_w, Q_b, conv_w, loc_proj_w, V_w,
                                        qbuf, effw, vwt);
    energy_kernel<<<dim3(32, 64), 256, 0, stream>>>(values, cum, qbuf, effw, vwt,
                                                    v_w, energies);
    softmax_kernel<<<B_, 256, 0, stream>>>(energies, mask, out);
    context_kernel<<<B_ * 8, 256, 0, stream>>>(values, out + B_ * ENC_, out);
}

// Round 2
// 524.511 us; speedup vs baseline: 1.3645x; 1.3645x over previous
//
#include <hip/hip_runtime.h>
#include <hip/hip_bf16.h>
#include <math.h>

// Problem constants
#define B_  64
#define T_  2048
#define DEC_ 1024
#define ENC_ 512
#define ATT_ 128
#define LOC_ 32
#define KW_  31

typedef __attribute__((ext_vector_type(8))) short short8;
typedef __attribute__((ext_vector_type(4))) float f32x4;

__device__ inline unsigned short bf16_rn(float x) {
    unsigned int u = __builtin_bit_cast(unsigned int, x);
    unsigned int r = u + 0x7fffu + ((u >> 16) & 1u);
    return (unsigned short)(r >> 16);
}
__device__ inline float bf16_to_f(unsigned short h) {
    unsigned int u = ((unsigned int)h) << 16;
    return __builtin_bit_cast(float, u);
}

// ---------------------------------------------------------------------------
// K1: prep
//  blocks 0..63   : qbuf[b][a] = query[b] . Q_w[a] + Q_b[a]   (wave-per-row)
//  block  64      : effT[n][k] (k=0..31, k=31 zero) = sum_c loc_proj[n,c]*conv_w[c,k]
//                   -> bf16 hi/lo, n-major (B-operand layout for loc MFMA)
//  blocks 65..96  : V_w (a-major [a][e]) -> bf16 hi/lo  (B-operand layout)
// ---------------------------------------------------------------------------
__global__ __launch_bounds__(256) void prep_kernel(
    const float* __restrict__ query, const float* __restrict__ Q_w,
    const float* __restrict__ Q_b, const float* __restrict__ conv_w,
    const float* __restrict__ loc_proj_w, const float* __restrict__ V_w,
    float* __restrict__ qbuf,
    unsigned short* __restrict__ Bhi, unsigned short* __restrict__ Blo,
    unsigned short* __restrict__ effThi, unsigned short* __restrict__ effTlo)
{
    int bi = blockIdx.x, tid = threadIdx.x;
    if (bi < B_) {
        __shared__ float sq[DEC_];
        *(float4*)(&sq[tid * 4]) = *(const float4*)(query + bi * DEC_ + tid * 4);
        __syncthreads();
        int w = tid >> 6, lane = tid & 63;
        for (int a = w * 32; a < w * 32 + 32; ++a) {
            const float* row = Q_w + (size_t)a * DEC_;
            float s = 0.f;
            #pragma unroll
            for (int i = 0; i < 4; ++i) {
                float4 qw = *(const float4*)(row + i * 256 + lane * 4);
                float4 xq = *(const float4*)(sq + i * 256 + lane * 4);
                s += qw.x * xq.x + qw.y * xq.y + qw.z * xq.z + qw.w * xq.w;
            }
            #pragma unroll
            for (int m = 32; m >= 1; m >>= 1) s += __shfl_xor(s, m, 64);
            if (lane == 0) qbuf[bi * ATT_ + a] = s + Q_b[a];
        }
    } else if (bi == B_) {
        if (tid < ATT_) {
            int n = tid;
            for (int k = 0; k < 32; ++k) {
                float s = 0.f;
                if (k < KW_)
                    for (int c = 0; c < LOC_; ++c)
                        s += loc_proj_w[n * LOC_ + c] * conv_w[c * KW_ + k];
                unsigned short h = bf16_rn(s);
                float lo = s - bf16_to_f(h);
                effThi[n * 32 + k] = h;
                effTlo[n * 32 + k] = bf16_rn(lo);
            }
        }
    } else {
        // convert V_w: 65536 elems, 32 blocks x 256 thr x 2 float4
        int g0 = (bi - B_ - 1) * 512;
        #pragma unroll
        for (int p = 0; p < 2; ++p) {
            int gi = g0 + p * 256 + tid;
            float4 v = ((const float4*)V_w)[gi];
            ushort4 h4, l4;
            h4.x = bf16_rn(v.x); l4.x = bf16_rn(v.x - bf16_to_f(h4.x));
            h4.y = bf16_rn(v.y); l4.y = bf16_rn(v.y - bf16_to_f(h4.y));
            h4.z = bf16_rn(v.z); l4.z = bf16_rn(v.z - bf16_to_f(h4.z));
            h4.w = bf16_rn(v.w); l4.w = bf16_rn(v.w - bf16_to_f(h4.w));
            *(ushort4*)(Bhi + (size_t)gi * 4) = h4;
            *(ushort4*)(Blo + (size_t)gi * 4) = l4;
        }
    }
}

// ---------------------------------------------------------------------------
// K2: energies via split-bf16 MFMA.
//  GEMM: M=B*T=131072, N=ATT=128, K=ENC=512.  Block tile 128x128, KC=64.
//  acc += Ahi*Bhi + Ahi*Blo + Alo*Bhi   (3 mfma per (m,n,k) tile)
//  Then loc conv as a second MFMA GEMM (Toeplitz x * effT, K=32) into same acc.
//  Epilogue: +q, tanh, *v_w, reduce over n -> energies[b][t].
// ---------------------------------------------------------------------------
#define KC 64
#define LDA 72   // padded LDS row stride in shorts (144 B: 16B-aligned, debanked)

__global__ __launch_bounds__(256) void energy_kernel(
    const float* __restrict__ values, const float* __restrict__ cum,
    const float* __restrict__ qbuf,
    const unsigned short* __restrict__ Bhi, const unsigned short* __restrict__ Blo,
    const unsigned short* __restrict__ effThi, const unsigned short* __restrict__ effTlo,
    const float* __restrict__ vw, float* __restrict__ energies)
{
    __shared__ unsigned short sAh[128 * LDA];
    __shared__ unsigned short sAl[128 * LDA];
    __shared__ unsigned short sBh[128 * LDA];
    __shared__ unsigned short sBl[128 * LDA];
    __shared__ float sx[160];
    __shared__ float sred[256];

    const int tid = threadIdx.x;
    const int bx  = blockIdx.x;
    const int b   = bx >> 4;
    const int t0  = (bx & 15) * 128;

    if (tid < 128 + 2 * 15) {
        int g = t0 - 15 + tid;
        sx[tid] = (g >= 0 && g < T_) ? cum[b * T_ + g] : 0.f;
    }

    const int w      = tid >> 6;
    const int lane   = tid & 63;
    const int lane15 = lane & 15;
    const int quad   = lane >> 4;
    const int wm0    = (w & 1) * 64;
    const int wn0    = (w >> 1) * 64;

    f32x4 acc[4][4];
    #pragma unroll
    for (int i = 0; i < 4; ++i)
        #pragma unroll
        for (int j = 0; j < 4; ++j) acc[i][j] = (f32x4){0.f, 0.f, 0.f, 0.f};

    const float* aptr = values + ((size_t)b * T_ + t0) * ENC_;

    for (int kc = 0; kc < ENC_; kc += KC) {
        __syncthreads();
        // stage A: 128 rows x 64 cols fp32 -> hi/lo bf16. 2048 float4, 8/thread.
        #pragma unroll
        for (int p = 0; p < 8; ++p) {
            int fi = p * 256 + tid;
            int r = fi >> 4, c4 = (fi & 15) * 4;
            float4 v = *(const float4*)(aptr + (size_t)r * ENC_ + kc + c4);
            ushort4 h4, l4;
            h4.x = bf16_rn(v.x); l4.x = bf16_rn(v.x - bf16_to_f(h4.x));
            h4.y = bf16_rn(v.y); l4.y = bf16_rn(v.y - bf16_to_f(h4.y));
            h4.z = bf16_rn(v.z); l4.z = bf16_rn(v.z - bf16_to_f(h4.z));
            h4.w = bf16_rn(v.w); l4.w = bf16_rn(v.w - bf16_to_f(h4.w));
            *(ushort4*)(&sAh[r * LDA + c4]) = h4;
            *(ushort4*)(&sAl[r * LDA + c4]) = l4;
        }
        // stage B: 128 n-rows x 64 k (bf16 preconverted). 2 threads/row.
        {
            int n = tid >> 1, koff = (tid & 1) * 32;
            const unsigned short* srch = Bhi + (size_t)n * ENC_ + kc + koff;
            const unsigned short* srcl = Blo + (size_t)n * ENC_ + kc + koff;
            #pragma unroll
            for (int q4 = 0; q4 < 4; ++q4) {
                *(uint4*)(&sBh[n * LDA + koff + q4 * 8]) = *(const uint4*)(srch + q4 * 8);
                *(uint4*)(&sBl[n * LDA + koff + q4 * 8]) = *(const uint4*)(srcl + q4 * 8);
            }
        }
        __syncthreads();

        #pragma unroll
        for (int ks = 0; ks < KC; ks += 32) {
            const int base = ks + quad * 8;
            short8 ah[4], al[4], bh[4], bl[4];
            #pragma unroll
            for (int i = 0; i < 4; ++i) {
                int row = (wm0 + i * 16 + lane15) * LDA + base;
                ah[i] = *(const short8*)(&sAh[row]);
                al[i] = *(const short8*)(&sAl[row]);
            }
            #pragma unroll
            for (int j = 0; j < 4; ++j) {
                int row = (wn0 + j * 16 + lane15) * LDA + base;
                bh[j] = *(const short8*)(&sBh[row]);
                bl[j] = *(const short8*)(&sBl[row]);
            }
            #pragma unroll
            for (int i = 0; i < 4; ++i)
                #pragma unroll
                for (int j = 0; j < 4; ++j) {
                    acc[i][j] = __builtin_amdgcn_mfma_f32_16x16x32_bf16(ah[i], bh[j], acc[i][j], 0, 0, 0);
                    acc[i][j] = __builtin_amdgcn_mfma_f32_16x16x32_bf16(ah[i], bl[j], acc[i][j], 0, 0, 0);
                    acc[i][j] = __builtin_amdgcn_mfma_f32_16x16x32_bf16(al[i], bh[j], acc[i][j], 0, 0, 0);
                }
        }
    }

    // ---- loc conv as MFMA: A' Toeplitz (128t x 32k), B' = effT (32k x 128n) ----
    __syncthreads();
    #pragma unroll
    for (int p = 0; p < 16; ++p) {
        int idx = p * 256 + tid;
        int r = idx >> 5, k = idx & 31;
        float xv = (k < KW_) ? sx[r + k] : 0.f;   // x[t0 + r + k - 15]
        unsigned short h = bf16_rn(xv);
        sAh[r * LDA + k] = h;
        sAl[r * LDA + k] = bf16_rn(xv - bf16_to_f(h));
        sBh[r * LDA + k] = effThi[idx];           // r == n here (idx>>5)
        sBl[r * LDA + k] = effTlo[idx];
    }
    __syncthreads();
    {
        const int base = quad * 8;
        short8 ah[4], al[4], bh[4], bl[4];
        #pragma unroll
        for (int i = 0; i < 4; ++i) {
            int row = (wm0 + i * 16 + lane15) * LDA + base;
            ah[i] = *(const short8*)(&sAh[row]);
            al[i] = *(const short8*)(&sAl[row]);
        }
        #pragma unroll
        for (int j = 0; j < 4; ++j) {
            int row = (wn0 + j * 16 + lane15) * LDA + base;
            bh[j] = *(const short8*)(&sBh[row]);
            bl[j] = *(const short8*)(&sBl[row]);
        }
        #pragma unroll
        for (int i = 0; i < 4; ++i)
            #pragma unroll
            for (int j = 0; j < 4; ++j) {
                acc[i][j] = __builtin_amdgcn_mfma_f32_16x16x32_bf16(ah[i], bh[j], acc[i][j], 0, 0, 0);
                acc[i][j] = __builtin_amdgcn_mfma_f32_16x16x32_bf16(ah[i], bl[j], acc[i][j], 0, 0, 0);
                acc[i][j] = __builtin_amdgcn_mfma_f32_16x16x32_bf16(al[i], bh[j], acc[i][j], 0, 0, 0);
            }
    }

    // ---- epilogue: z = acc + q[n]; e = sum_n vw[n]*tanh(z) ----
    float qv[4], vv[4];
    #pragma unroll
    for (int j = 0; j < 4; ++j) {
        int n = wn0 + j * 16 + lane15;
        qv[j] = qbuf[b * ATT_ + n];
        vv[j] = vw[n];
    }
    #pragma unroll
    for (int i = 0; i < 4; ++i) {
        #pragma unroll
        for (int reg = 0; reg < 4; ++reg) {
            float s = 0.f;
            #pragma unroll
            for (int j = 0; j < 4; ++j) {
                float z = acc[i][j][reg] + qv[j];
                s += vv[j] * tanhf(z);
            }
            #pragma unroll
            for (int m = 8; m >= 1; m >>= 1) s += __shfl_xor(s, m, 64);
            if (lane15 == 0)
                sred[(w >> 1) * 128 + wm0 + i * 16 + quad * 4 + reg] = s;
        }
    }
    __syncthreads();
    if (tid < 128)
        energies[b * T_ + t0 + tid] = sred[tid] + sred[128 + tid];
}

// ---------------------------------------------------------------------------
// K3: softmax over T per b; also zeroes ctx region for K4 atomics.
// ---------------------------------------------------------------------------
__global__ __launch_bounds__(256) void softmax_kernel(
    const float* __restrict__ energies, const unsigned char* __restrict__ mask,
    float* __restrict__ out)
{
    int b = blockIdx.x, tid = threadIdx.x;
    float* ctx  = out;                 // B*ENC
    float* wout = out + B_ * ENC_;     // B*T

    for (int i = tid; i < ENC_; i += 256) ctx[b * ENC_ + i] = 0.f;

    float e[8];
    float mx = -INFINITY;
    #pragma unroll
    for (int p = 0; p < 8; ++p) {
        int t = p * 256 + tid;
        float v = energies[b * T_ + t];
        if (mask[b * T_ + t]) v = -INFINITY;
        e[p] = v;
        mx = fmaxf(mx, v);
    }
    #pragma unroll
    for (int m = 32; m >= 1; m >>= 1) mx = fmaxf(mx, __shfl_xor(mx, m, 64));
    __shared__ float red[8];
    int wave = tid >> 6;
    if ((tid & 63) == 0) red[wave] = mx;
    __syncthreads();
    mx = fmaxf(fmaxf(red[0], red[1]), fmaxf(red[2], red[3]));

    float sum = 0.f;
    #pragma unroll
    for (int p = 0; p < 8; ++p) {
        e[p] = expf(e[p] - mx);
        sum += e[p];
    }
    #pragma unroll
    for (int m = 32; m >= 1; m >>= 1) sum += __shfl_xor(sum, m, 64);
    if ((tid & 63) == 0) red[4 + wave] = sum;
    __syncthreads();
    sum = red[4] + red[5] + red[6] + red[7];
    float inv = 1.f / sum;
    #pragma unroll
    for (int p = 0; p < 8; ++p)
        wout[b * T_ + p * 256 + tid] = e[p] * inv;
}

// ---------------------------------------------------------------------------
// K4: context[b,e] = sum_t w[b,t] * values[b,t,e]
// ---------------------------------------------------------------------------
__global__ __launch_bounds__(256) void context_kernel(
    const float* __restrict__ values, const float* __restrict__ w,
    float* __restrict__ ctx)
{
    int bs = blockIdx.x;
    int b = bs >> 3, seg = bs & 7;
    int tid = threadIdx.x;
    int tt = tid >> 7;
    int e4 = (tid & 127) * 4;

    __shared__ float sw[256];
    int tbase = seg * 256;
    sw[tid] = w[b * T_ + tbase + tid];
    __syncthreads();

    float4 acc = make_float4(0.f, 0.f, 0.f, 0.f);
    const float* vp = values + ((size_t)b * T_ + tbase) * ENC_ + e4;
    #pragma unroll 4
    for (int t = tt; t < 256; t += 2) {
        float4 v = *(const float4*)(vp + (size_t)t * ENC_);
        float wv = sw[t];
        acc.x += wv * v.x; acc.y += wv * v.y;
        acc.z += wv * v.z; acc.w += wv * v.w;
    }

    __shared__ float red[512];
    if (tt == 1) *(float4*)&red[e4] = acc;
    __syncthreads();
    if (tt == 0) {
        float4 o = *(const float4*)&red[e4];
        atomicAdd(&ctx[b * ENC_ + e4 + 0], acc.x + o.x);
        atomicAdd(&ctx[b * ENC_ + e4 + 1], acc.y + o.y);
        atomicAdd(&ctx[b * ENC_ + e4 + 2], acc.z + o.z);
        atomicAdd(&ctx[b * ENC_ + e4 + 3], acc.w + o.w);
    }
}

// ---------------------------------------------------------------------------
extern "C" void kernel_launch(void* const* d_in, const int* in_sizes, int n_in,
                              void* d_out, int out_size, void* d_ws, size_t ws_size,
                              hipStream_t stream) {
    const float* query        = (const float*)d_in[0];
    const float* values       = (const float*)d_in[1];
    const float* cum          = (const float*)d_in[2];
    const unsigned char* mask = (const unsigned char*)d_in[3];
    const float* Q_w          = (const float*)d_in[4];
    const float* Q_b          = (const float*)d_in[5];
    const float* V_w          = (const float*)d_in[6];
    const float* conv_w       = (const float*)d_in[7];
    const float* loc_proj_w   = (const float*)d_in[8];
    const float* v_w          = (const float*)d_in[9];

    float* out = (float*)d_out;
    char*  ws  = (char*)d_ws;
    // ws layout (bytes):
    //  qbuf     @ 0        (8192 f  = 32 KB)
    //  energies @ 32768    (131072 f = 512 KB)
    //  Bhi      @ 557056   (65536 us = 128 KB)
    //  Blo      @ 688128   (128 KB)
    //  effThi   @ 819200   (4096 us = 8 KB)
    //  effTlo   @ 827392   (8 KB)   -> total 835584 B
    float*          qbuf     = (float*)(ws);
    float*          energies = (float*)(ws + 32768);
    unsigned short* Bhi      = (unsigned short*)(ws + 557056);
    unsigned short* Blo      = (unsigned short*)(ws + 688128);
    unsigned short* effThi   = (unsigned short*)(ws + 819200);
    unsigned short* effTlo   = (unsigned short*)(ws + 827392);

    prep_kernel<<<97, 256, 0, stream>>>(query, Q_w, Q_b, conv_w, loc_proj_w, V_w,
                                        qbuf, Bhi, Blo, effThi, effTlo);
    energy_kernel<<<1024, 256, 0, stream>>>(values, cum, qbuf, Bhi, Blo,
                                            effThi, effTlo, v_w, energies);
    softmax_kernel<<<B_, 256, 0, stream>>>(energies, mask, out);
    context_kernel<<<B_ * 8, 256, 0, stream>>>(values, out + B_ * ENC_, out);
}

// Round 3
// 493.164 us; speedup vs baseline: 1.4512x; 1.0636x over previous
//
#include <hip/hip_runtime.h>
#include <hip/hip_bf16.h>
#include <math.h>

// Problem constants
#define B_  64
#define T_  2048
#define DEC_ 1024
#define ENC_ 512
#define ATT_ 128
#define LOC_ 32
#define KW_  31

typedef __attribute__((ext_vector_type(8))) short short8;
typedef __attribute__((ext_vector_type(4))) float f32x4;

__device__ inline unsigned short bf16_rn(float x) {
    unsigned int u = __builtin_bit_cast(unsigned int, x);
    unsigned int r = u + 0x7fffu + ((u >> 16) & 1u);
    return (unsigned short)(r >> 16);
}
__device__ inline float bf16_to_f(unsigned short h) {
    unsigned int u = ((unsigned int)h) << 16;
    return __builtin_bit_cast(float, u);
}

// ---------------------------------------------------------------------------
// K1: prep
//  blocks 0..63 : qbuf[b][a] = query[b].Q_w[a] + Q_b[a] (wave-per-2-rows)
//  block  64    : eff[n][k] (k=31 zero-padded) -> bf16 hi/lo at effh/effl[n*32+k]
//  blocks 65..96: V_w -> bf16 hi/lo packed fragment layout:
//                 Bp[(k>>5)*4096 + n*32 + (k&31)]  (1 KB coalesced frag reads)
// ---------------------------------------------------------------------------
__global__ __launch_bounds__(256) void prep_kernel(
    const float* __restrict__ query, const float* __restrict__ Q_w,
    const float* __restrict__ Q_b, const float* __restrict__ conv_w,
    const float* __restrict__ loc_proj_w, const float* __restrict__ V_w,
    float* __restrict__ qbuf,
    unsigned short* __restrict__ Bph, unsigned short* __restrict__ Bpl,
    unsigned short* __restrict__ effh, unsigned short* __restrict__ effl)
{
    int bi = blockIdx.x, tid = threadIdx.x;
    if (bi < B_) {
        __shared__ float sq[DEC_];
        *(float4*)(&sq[tid * 4]) = *(const float4*)(query + bi * DEC_ + tid * 4);
        __syncthreads();
        int w = tid >> 6, lane = tid & 63;
        for (int a = w * 32; a < w * 32 + 32; a += 2) {
            const float* r0 = Q_w + (size_t)a * DEC_;
            const float* r1 = r0 + DEC_;
            float s0 = 0.f, s1 = 0.f;
            #pragma unroll
            for (int i = 0; i < 4; ++i) {
                float4 q0 = *(const float4*)(r0 + i * 256 + lane * 4);
                float4 q1 = *(const float4*)(r1 + i * 256 + lane * 4);
                float4 xq = *(const float4*)(sq + i * 256 + lane * 4);
                s0 += q0.x * xq.x + q0.y * xq.y + q0.z * xq.z + q0.w * xq.w;
                s1 += q1.x * xq.x + q1.y * xq.y + q1.z * xq.z + q1.w * xq.w;
            }
            #pragma unroll
            for (int m = 32; m >= 1; m >>= 1) {
                s0 += __shfl_xor(s0, m, 64);
                s1 += __shfl_xor(s1, m, 64);
            }
            if (lane == 0) {
                qbuf[bi * ATT_ + a]     = s0 + Q_b[a];
                qbuf[bi * ATT_ + a + 1] = s1 + Q_b[a + 1];
            }
        }
    } else if (bi == B_) {
        __shared__ float slp[ATT_ * LOC_];   // 16 KB  [n][c]
        __shared__ float scw[LOC_ * KW_];    // [c][k]
        for (int i = tid; i < ATT_ * LOC_; i += 256) slp[i] = loc_proj_w[i];
        for (int i = tid; i < LOC_ * KW_; i += 256) scw[i] = conv_w[i];
        __syncthreads();
        if (tid < ATT_) {
            int n = tid;
            for (int k = 0; k < 32; ++k) {
                float s = 0.f;
                if (k < KW_)
                    #pragma unroll
                    for (int c = 0; c < LOC_; ++c)
                        s += slp[n * LOC_ + c] * scw[c * KW_ + k];
                unsigned short h = bf16_rn(s);
                effh[n * 32 + k] = h;
                effl[n * 32 + k] = bf16_rn(s - bf16_to_f(h));
            }
        }
    } else {
        // V_w: 16384 float4s across 32 blocks
        int g0 = (bi - B_ - 1) * 512;
        #pragma unroll
        for (int p = 0; p < 2; ++p) {
            int gi = g0 + p * 256 + tid;
            int n  = gi >> 7;            // row (a index)
            int kq = (gi & 127) * 4;     // first k of this float4
            float4 v = ((const float4*)V_w)[gi];
            ushort4 h4, l4;
            h4.x = bf16_rn(v.x); l4.x = bf16_rn(v.x - bf16_to_f(h4.x));
            h4.y = bf16_rn(v.y); l4.y = bf16_rn(v.y - bf16_to_f(h4.y));
            h4.z = bf16_rn(v.z); l4.z = bf16_rn(v.z - bf16_to_f(h4.z));
            h4.w = bf16_rn(v.w); l4.w = bf16_rn(v.w - bf16_to_f(h4.w));
            int dst = (kq >> 5) * 4096 + n * 32 + (kq & 31);
            *(ushort4*)(Bph + dst) = h4;
            *(ushort4*)(Bpl + dst) = l4;
        }
    }
}

// ---------------------------------------------------------------------------
// K2: energies via split-bf16 MFMA. A (values) staged in LDS hi/lo with
// register prefetch of the next chunk; B fragments read directly from the
// L2-resident packed arrays (coalesced 1 KB wave reads). LDS ~38.5 KB,
// __launch_bounds__(256,3) -> 3 blocks/CU.
// ---------------------------------------------------------------------------
#define KC 64
#define LDA 72   // padded LDS row stride in shorts (144 B -> 2-way max on b128)

__global__ __launch_bounds__(256, 3) void energy_kernel(
    const float* __restrict__ values, const float* __restrict__ cum,
    const float* __restrict__ qbuf,
    const unsigned short* __restrict__ Bph, const unsigned short* __restrict__ Bpl,
    const unsigned short* __restrict__ effh, const unsigned short* __restrict__ effl,
    const float* __restrict__ vw, float* __restrict__ energies)
{
    __shared__ unsigned short sAh[128 * LDA];
    __shared__ unsigned short sAl[128 * LDA];
    __shared__ float sx[160];
    __shared__ float sred[256];

    const int tid = threadIdx.x;
    const int bx  = blockIdx.x;
    const int b   = bx >> 4;
    const int t0  = (bx & 15) * 128;

    if (tid < 158) {
        int g = t0 - 15 + tid;
        sx[tid] = (g >= 0 && g < T_) ? cum[b * T_ + g] : 0.f;
    }

    const int w      = tid >> 6;
    const int lane   = tid & 63;
    const int lane15 = lane & 15;
    const int quad   = lane >> 4;
    const int wm0    = (w & 1) * 64;
    const int wn0    = (w >> 1) * 64;

    f32x4 acc[4][4];
    #pragma unroll
    for (int i = 0; i < 4; ++i)
        #pragma unroll
        for (int j = 0; j < 4; ++j) acc[i][j] = (f32x4){0.f, 0.f, 0.f, 0.f};

    const float* aptr = values + ((size_t)b * T_ + t0) * ENC_;
    const int ar = tid >> 4;          // row within 16-row group
    const int ac = (tid & 15) * 4;    // col (float)

    // prefetch chunk 0
    float4 pf[8];
    #pragma unroll
    for (int p = 0; p < 8; ++p)
        pf[p] = *(const float4*)(aptr + (size_t)(p * 16 + ar) * ENC_ + ac);

    for (int kc = 0; kc < ENC_; kc += KC) {
        __syncthreads();
        // convert prefetched chunk -> LDS hi/lo
        #pragma unroll
        for (int p = 0; p < 8; ++p) {
            int r = p * 16 + ar;
            float4 v = pf[p];
            ushort4 h4, l4;
            h4.x = bf16_rn(v.x); l4.x = bf16_rn(v.x - bf16_to_f(h4.x));
            h4.y = bf16_rn(v.y); l4.y = bf16_rn(v.y - bf16_to_f(h4.y));
            h4.z = bf16_rn(v.z); l4.z = bf16_rn(v.z - bf16_to_f(h4.z));
            h4.w = bf16_rn(v.w); l4.w = bf16_rn(v.w - bf16_to_f(h4.w));
            *(ushort4*)(&sAh[r * LDA + ac]) = h4;
            *(ushort4*)(&sAl[r * LDA + ac]) = l4;
        }
        __syncthreads();
        // issue next chunk's loads; vmcnt wait lands after the MFMA block
        if (kc + KC < ENC_) {
            #pragma unroll
            for (int p = 0; p < 8; ++p)
                pf[p] = *(const float4*)(aptr + (size_t)(p * 16 + ar) * ENC_ + kc + KC + ac);
        }
        #pragma unroll
        for (int ks = 0; ks < KC; ks += 32) {
            const int base  = ks + quad * 8;
            const int chunk = ((kc + ks) >> 5) * 4096;
            short8 ah[4], al[4];
            #pragma unroll
            for (int i = 0; i < 4; ++i) {
                int row = (wm0 + i * 16 + lane15) * LDA + base;
                ah[i] = *(const short8*)(&sAh[row]);
                al[i] = *(const short8*)(&sAl[row]);
            }
            #pragma unroll
            for (int j = 0; j < 4; ++j) {
                int n = wn0 + j * 16 + lane15;
                short8 bh = *(const short8*)(Bph + chunk + n * 32 + quad * 8);
                short8 bl = *(const short8*)(Bpl + chunk + n * 32 + quad * 8);
                #pragma unroll
                for (int i = 0; i < 4; ++i) {
                    acc[i][j] = __builtin_amdgcn_mfma_f32_16x16x32_bf16(ah[i], bh, acc[i][j], 0, 0, 0);
                    acc[i][j] = __builtin_amdgcn_mfma_f32_16x16x32_bf16(ah[i], bl, acc[i][j], 0, 0, 0);
                    acc[i][j] = __builtin_amdgcn_mfma_f32_16x16x32_bf16(al[i], bh, acc[i][j], 0, 0, 0);
                }
            }
        }
    }

    // ---- loc conv as MFMA: A' Toeplitz (128t x 32k) in LDS, B' = eff from L2 ----
    __syncthreads();
    #pragma unroll
    for (int p = 0; p < 16; ++p) {
        int idx = p * 256 + tid;
        int r = idx >> 5, k = idx & 31;
        float xv = (k < KW_) ? sx[r + k] : 0.f;   // x[t0 + r + k - 15]
        unsigned short h = bf16_rn(xv);
        sAh[r * LDA + k] = h;
        sAl[r * LDA + k] = bf16_rn(xv - bf16_to_f(h));
    }
    __syncthreads();
    {
        const int base = quad * 8;
        short8 ah[4], al[4];
        #pragma unroll
        for (int i = 0; i < 4; ++i) {
            int row = (wm0 + i * 16 + lane15) * LDA + base;
            ah[i] = *(const short8*)(&sAh[row]);
            al[i] = *(const short8*)(&sAl[row]);
        }
        #pragma unroll
        for (int j = 0; j < 4; ++j) {
            int n = wn0 + j * 16 + lane15;
            short8 bh = *(const short8*)(effh + n * 32 + base);
            short8 bl = *(const short8*)(effl + n * 32 + base);
            #pragma unroll
            for (int i = 0; i < 4; ++i) {
                acc[i][j] = __builtin_amdgcn_mfma_f32_16x16x32_bf16(ah[i], bh, acc[i][j], 0, 0, 0);
                acc[i][j] = __builtin_amdgcn_mfma_f32_16x16x32_bf16(ah[i], bl, acc[i][j], 0, 0, 0);
                acc[i][j] = __builtin_amdgcn_mfma_f32_16x16x32_bf16(al[i], bh, acc[i][j], 0, 0, 0);
            }
        }
    }

    // ---- epilogue: z = acc + q[n]; e = sum_n vw[n]*tanh(z) ----
    float qv[4], vv[4];
    #pragma unroll
    for (int j = 0; j < 4; ++j) {
        int n = wn0 + j * 16 + lane15;
        qv[j] = qbuf[b * ATT_ + n];
        vv[j] = vw[n];
    }
    #pragma unroll
    for (int i = 0; i < 4; ++i) {
        #pragma unroll
        for (int reg = 0; reg < 4; ++reg) {
            float s = 0.f;
            #pragma unroll
            for (int j = 0; j < 4; ++j) {
                float z = acc[i][j][reg] + qv[j];
                s += vv[j] * tanhf(z);
            }
            #pragma unroll
            for (int m = 8; m >= 1; m >>= 1) s += __shfl_xor(s, m, 64);
            if (lane15 == 0)
                sred[(w >> 1) * 128 + wm0 + i * 16 + quad * 4 + reg] = s;
        }
    }
    __syncthreads();
    if (tid < 128)
        energies[b * T_ + t0 + tid] = sred[tid] + sred[128 + tid];
}

// ---------------------------------------------------------------------------
// K3: softmax over T per b; zeroes ctx region for K4 atomics.
// ---------------------------------------------------------------------------
__global__ __launch_bounds__(256) void softmax_kernel(
    const float* __restrict__ energies, const unsigned char* __restrict__ mask,
    float* __restrict__ out)
{
    int b = blockIdx.x, tid = threadIdx.x;
    float* ctx  = out;                 // B*ENC
    float* wout = out + B_ * ENC_;     // B*T

    for (int i = tid; i < ENC_; i += 256) ctx[b * ENC_ + i] = 0.f;

    float e[8];
    float mx = -INFINITY;
    #pragma unroll
    for (int p = 0; p < 8; ++p) {
        int t = p * 256 + tid;
        float v = energies[b * T_ + t];
        if (mask[b * T_ + t]) v = -INFINITY;
        e[p] = v;
        mx = fmaxf(mx, v);
    }
    #pragma unroll
    for (int m = 32; m >= 1; m >>= 1) mx = fmaxf(mx, __shfl_xor(mx, m, 64));
    __shared__ float red[8];
    int wave = tid >> 6;
    if ((tid & 63) == 0) red[wave] = mx;
    __syncthreads();
    mx = fmaxf(fmaxf(red[0], red[1]), fmaxf(red[2], red[3]));

    float sum = 0.f;
    #pragma unroll
    for (int p = 0; p < 8; ++p) {
        e[p] = expf(e[p] - mx);
        sum += e[p];
    }
    #pragma unroll
    for (int m = 32; m >= 1; m >>= 1) sum += __shfl_xor(sum, m, 64);
    if ((tid & 63) == 0) red[4 + wave] = sum;
    __syncthreads();
    sum = red[4] + red[5] + red[6] + red[7];
    float inv = 1.f / sum;
    #pragma unroll
    for (int p = 0; p < 8; ++p)
        wout[b * T_ + p * 256 + tid] = e[p] * inv;
}

// ---------------------------------------------------------------------------
// K4: context[b,e] = sum_t w[b,t]*values[b,t,e].  1024 blocks (4/CU),
// 128-t segment per block, 64 independent float4 loads/thread.
// ---------------------------------------------------------------------------
__global__ __launch_bounds__(256) void context_kernel(
    const float* __restrict__ values, const float* __restrict__ w,
    float* __restrict__ ctx)
{
    int bx = blockIdx.x;
    int b = bx >> 4, seg = bx & 15;
    int tid = threadIdx.x;
    int tt = tid >> 7;                 // 0..1
    int e4 = (tid & 127) * 4;

    __shared__ float sw[128];
    if (tid < 128) sw[tid] = w[b * T_ + seg * 128 + tid];
    __syncthreads();

    const float* vp = values + ((size_t)b * T_ + seg * 128) * ENC_ + e4;
    float4 acc = make_float4(0.f, 0.f, 0.f, 0.f);
    #pragma unroll 8
    for (int t = 0; t < 64; ++t) {
        int tg = tt * 64 + t;
        float4 v = *(const float4*)(vp + (size_t)tg * ENC_);
        float wv = sw[tg];
        acc.x += wv * v.x; acc.y += wv * v.y;
        acc.z += wv * v.z; acc.w += wv * v.w;
    }

    __shared__ float red[512];
    if (tt == 1) *(float4*)&red[e4] = acc;
    __syncthreads();
    if (tt == 0) {
        float4 o = *(const float4*)&red[e4];
        atomicAdd(&ctx[b * ENC_ + e4 + 0], acc.x + o.x);
        atomicAdd(&ctx[b * ENC_ + e4 + 1], acc.y + o.y);
        atomicAdd(&ctx[b * ENC_ + e4 + 2], acc.z + o.z);
        atomicAdd(&ctx[b * ENC_ + e4 + 3], acc.w + o.w);
    }
}

// ---------------------------------------------------------------------------
extern "C" void kernel_launch(void* const* d_in, const int* in_sizes, int n_in,
                              void* d_out, int out_size, void* d_ws, size_t ws_size,
                              hipStream_t stream) {
    const float* query        = (const float*)d_in[0];
    const float* values       = (const float*)d_in[1];
    const float* cum          = (const float*)d_in[2];
    const unsigned char* mask = (const unsigned char*)d_in[3];
    const float* Q_w          = (const float*)d_in[4];
    const float* Q_b          = (const float*)d_in[5];
    const float* V_w          = (const float*)d_in[6];
    const float* conv_w       = (const float*)d_in[7];
    const float* loc_proj_w   = (const float*)d_in[8];
    const float* v_w          = (const float*)d_in[9];

    float* out = (float*)d_out;
    char*  ws  = (char*)d_ws;
    // ws layout (bytes):
    //  qbuf @0 (32 KB) | energies @32768 (512 KB) | Bph @557056 (128 KB)
    //  Bpl @688128 (128 KB) | effh @819200 (8 KB) | effl @827392 (8 KB)
    float*          qbuf     = (float*)(ws);
    float*          energies = (float*)(ws + 32768);
    unsigned short* Bph      = (unsigned short*)(ws + 557056);
    unsigned short* Bpl      = (unsigned short*)(ws + 688128);
    unsigned short* effh     = (unsigned short*)(ws + 819200);
    unsigned short* effl     = (unsigned short*)(ws + 827392);

    prep_kernel<<<97, 256, 0, stream>>>(query, Q_w, Q_b, conv_w, loc_proj_w, V_w,
                                        qbuf, Bph, Bpl, effh, effl);
    energy_kernel<<<1024, 256, 0, stream>>>(values, cum, qbuf, Bph, Bpl,
                                            effh, effl, v_w, energies);
    softmax_kernel<<<B_, 256, 0, stream>>>(energies, mask, out);
    context_kernel<<<B_ * 16, 256, 0, stream>>>(values, out + B_ * ENC_, out);
}

// Round 5
// 479.840 us; speedup vs baseline: 1.4915x; 1.0278x over previous
//
#include <hip/hip_runtime.h>
#include <hip/hip_bf16.h>
#include <math.h>

// Problem constants
#define B_  64
#define T_  2048
#define DEC_ 1024
#define ENC_ 512
#define ATT_ 128
#define LOC_ 32
#define KW_  31

typedef __attribute__((ext_vector_type(8))) short short8;
typedef __attribute__((ext_vector_type(4))) float f32x4;

__device__ inline unsigned short bf16_rn(float x) {
    unsigned int u = __builtin_bit_cast(unsigned int, x);
    unsigned int r = u + 0x7fffu + ((u >> 16) & 1u);
    return (unsigned short)(r >> 16);
}
__device__ inline float bf16_to_f(unsigned short h) {
    unsigned int u = ((unsigned int)h) << 16;
    return __builtin_bit_cast(float, u);
}
__device__ inline void cvt_pair(float4 a, float4 b2, short8& hi, short8& lo) {
    float f[8] = {a.x, a.y, a.z, a.w, b2.x, b2.y, b2.z, b2.w};
    #pragma unroll
    for (int j = 0; j < 8; ++j) {
        unsigned short h = bf16_rn(f[j]);
        hi[j] = (short)h;
        lo[j] = (short)bf16_rn(f[j] - bf16_to_f(h));
    }
}

// ---------------------------------------------------------------------------
// K1: prep
//  blocks 0..255  : qbuf[b][a] = query[b].Q_w[a]+Q_b[a]  (b=bi>>2, wave-per-8-rows)
//  block  256     : eff[n][k] (k=31 zero) -> bf16 hi/lo at effh/effl[n*32+k]
//  blocks 257..288: V_w -> bf16 hi/lo packed frag layout Bp[(k>>5)*4096+n*32+(k&31)]
// ---------------------------------------------------------------------------
__global__ __launch_bounds__(256) void prep_kernel(
    const float* __restrict__ query, const float* __restrict__ Q_w,
    const float* __restrict__ Q_b, const float* __restrict__ conv_w,
    const float* __restrict__ loc_proj_w, const float* __restrict__ V_w,
    float* __restrict__ qbuf,
    unsigned short* __restrict__ Bph, unsigned short* __restrict__ Bpl,
    unsigned short* __restrict__ effh, unsigned short* __restrict__ effl)
{
    int bi = blockIdx.x, tid = threadIdx.x;
    if (bi < 256) {
        int b = bi >> 2, grp = bi & 3;
        __shared__ float sq[DEC_];
        *(float4*)(&sq[tid * 4]) = *(const float4*)(query + (size_t)b * DEC_ + tid * 4);
        __syncthreads();
        int w = tid >> 6, lane = tid & 63;
        int a0 = grp * 32 + w * 8;
        for (int p = 0; p < 4; ++p) {
            int a = a0 + 2 * p;
            const float* r0 = Q_w + (size_t)a * DEC_;
            const float* r1 = r0 + DEC_;
            float s0 = 0.f, s1 = 0.f;
            #pragma unroll
            for (int i = 0; i < 4; ++i) {
                float4 q0 = *(const float4*)(r0 + i * 256 + lane * 4);
                float4 q1 = *(const float4*)(r1 + i * 256 + lane * 4);
                float4 xq = *(const float4*)(sq + i * 256 + lane * 4);
                s0 += q0.x * xq.x + q0.y * xq.y + q0.z * xq.z + q0.w * xq.w;
                s1 += q1.x * xq.x + q1.y * xq.y + q1.z * xq.z + q1.w * xq.w;
            }
            #pragma unroll
            for (int m = 32; m >= 1; m >>= 1) {
                s0 += __shfl_xor(s0, m, 64);
                s1 += __shfl_xor(s1, m, 64);
            }
            if (lane == 0) {
                qbuf[b * ATT_ + a]     = s0 + Q_b[a];
                qbuf[b * ATT_ + a + 1] = s1 + Q_b[a + 1];
            }
        }
    } else if (bi == 256) {
        __shared__ float slp[ATT_ * LOC_];
        __shared__ float scw[LOC_ * KW_];
        for (int i = tid; i < ATT_ * LOC_; i += 256) slp[i] = loc_proj_w[i];
        for (int i = tid; i < LOC_ * KW_; i += 256) scw[i] = conv_w[i];
        __syncthreads();
        if (tid < ATT_) {
            int n = tid;
            for (int k = 0; k < 32; ++k) {
                float s = 0.f;
                if (k < KW_)
                    #pragma unroll
                    for (int c = 0; c < LOC_; ++c)
                        s += slp[n * LOC_ + c] * scw[c * KW_ + k];
                unsigned short h = bf16_rn(s);
                effh[n * 32 + k] = h;
                effl[n * 32 + k] = bf16_rn(s - bf16_to_f(h));
            }
        }
    } else {
        int g0 = (bi - 257) * 512;
        #pragma unroll
        for (int p = 0; p < 2; ++p) {
            int gi = g0 + p * 256 + tid;
            int n  = gi >> 7;
            int kq = (gi & 127) * 4;
            float4 v = ((const float4*)V_w)[gi];
            ushort4 h4, l4;
            h4.x = bf16_rn(v.x); l4.x = bf16_rn(v.x - bf16_to_f(h4.x));
            h4.y = bf16_rn(v.y); l4.y = bf16_rn(v.y - bf16_to_f(h4.y));
            h4.z = bf16_rn(v.z); l4.z = bf16_rn(v.z - bf16_to_f(h4.z));
            h4.w = bf16_rn(v.w); l4.w = bf16_rn(v.w - bf16_to_f(h4.w));
            int dst = (kq >> 5) * 4096 + n * 32 + (kq & 31);
            *(ushort4*)(Bph + dst) = h4;
            *(ushort4*)(Bpl + dst) = l4;
        }
    }
}

// ---------------------------------------------------------------------------
// K2: energies via LDS-free direct-fragment split-bf16 MFMA.
//  Grid 1024 = (b, tchunk of 128). Each wave: M=32 rows, N=128, K=512.
//  B frags from L2-resident packed array, issued BEFORE the HBM A-prefetch
//  (vmcnt retires in order). No __syncthreads in the K-loop.
//  Epilogue: Toeplitz loc-conv MFMA + q + tanhf + v_w-dot -> energies (ws).
// ---------------------------------------------------------------------------
__global__ __launch_bounds__(256, 2) void energy_kernel(
    const float* __restrict__ values, const float* __restrict__ cum,
    const float* __restrict__ qbuf,
    const unsigned short* __restrict__ Bph, const unsigned short* __restrict__ Bpl,
    const unsigned short* __restrict__ effh, const unsigned short* __restrict__ effl,
    const float* __restrict__ vw, float* __restrict__ energies)
{
    __shared__ float sx[160];

    const int tid = threadIdx.x;
    const int bx  = blockIdx.x;
    const int b   = bx >> 4;
    const int t0  = (bx & 15) * 128;

    if (tid < 160) {
        int g = t0 - 15 + tid;
        sx[tid] = (g >= 0 && g < T_) ? cum[b * T_ + g] : 0.f;
    }
    __syncthreads();

    const int w      = tid >> 6;
    const int lane   = tid & 63;
    const int lane15 = lane & 15;
    const int quad   = lane >> 4;

    f32x4 acc[2][8];
    #pragma unroll
    for (int i = 0; i < 2; ++i)
        #pragma unroll
        for (int j = 0; j < 8; ++j) acc[i][j] = (f32x4){0.f, 0.f, 0.f, 0.f};

    const float* abase = values + ((size_t)b * T_ + t0 + w * 32 + lane15) * ENC_ + quad * 8;
    const unsigned short* bbh = Bph + lane15 * 32 + quad * 8;
    const unsigned short* bbl = Bpl + lane15 * 32 + quad * 8;

    float4 pf[2][2];
    #pragma unroll
    for (int i = 0; i < 2; ++i) {
        pf[i][0] = *(const float4*)(abase + i * 16 * ENC_);
        pf[i][1] = *(const float4*)(abase + i * 16 * ENC_ + 4);
    }

    for (int kc = 0; kc < ENC_; kc += 32) {
        short8 ah[2], al[2];
        #pragma unroll
        for (int i = 0; i < 2; ++i) cvt_pair(pf[i][0], pf[i][1], ah[i], al[i]);

        // B fragments (L2) issued BEFORE the HBM prefetch
        short8 bh[8], bl[8];
        const int chunk = (kc >> 5) * 4096;
        #pragma unroll
        for (int j = 0; j < 8; ++j) {
            bh[j] = *(const short8*)(bbh + chunk + j * 512);
            bl[j] = *(const short8*)(bbl + chunk + j * 512);
        }
        __builtin_amdgcn_sched_barrier(0);
        if (kc + 32 < ENC_) {
            #pragma unroll
            for (int i = 0; i < 2; ++i) {
                pf[i][0] = *(const float4*)(abase + i * 16 * ENC_ + kc + 32);
                pf[i][1] = *(const float4*)(abase + i * 16 * ENC_ + kc + 36);
            }
        }
        __builtin_amdgcn_sched_barrier(0);
        #pragma unroll
        for (int j = 0; j < 8; ++j)
            #pragma unroll
            for (int i = 0; i < 2; ++i) {
                acc[i][j] = __builtin_amdgcn_mfma_f32_16x16x32_bf16(ah[i], bh[j], acc[i][j], 0, 0, 0);
                acc[i][j] = __builtin_amdgcn_mfma_f32_16x16x32_bf16(ah[i], bl[j], acc[i][j], 0, 0, 0);
                acc[i][j] = __builtin_amdgcn_mfma_f32_16x16x32_bf16(al[i], bh[j], acc[i][j], 0, 0, 0);
            }
    }

    // ---- loc conv as MFMA: A' Toeplitz built from sx in-register ----
    {
        short8 ah[2], al[2];
        #pragma unroll
        for (int i = 0; i < 2; ++i) {
            int base = w * 32 + i * 16 + lane15 + quad * 8;
            #pragma unroll
            for (int j2 = 0; j2 < 8; ++j2) {
                float xv = sx[base + j2];           // k=31 column killed by eff==0
                unsigned short h = bf16_rn(xv);
                ah[i][j2] = (short)h;
                al[i][j2] = (short)bf16_rn(xv - bf16_to_f(h));
            }
        }
        #pragma unroll
        for (int j = 0; j < 8; ++j) {
            int n = j * 16 + lane15;
            short8 bh = *(const short8*)(effh + n * 32 + quad * 8);
            short8 bl = *(const short8*)(effl + n * 32 + quad * 8);
            #pragma unroll
            for (int i = 0; i < 2; ++i) {
                acc[i][j] = __builtin_amdgcn_mfma_f32_16x16x32_bf16(ah[i], bh, acc[i][j], 0, 0, 0);
                acc[i][j] = __builtin_amdgcn_mfma_f32_16x16x32_bf16(ah[i], bl, acc[i][j], 0, 0, 0);
                acc[i][j] = __builtin_amdgcn_mfma_f32_16x16x32_bf16(al[i], bh, acc[i][j], 0, 0, 0);
            }
        }
    }

    // ---- epilogue: E[t] = sum_n vw[n]*tanhf(acc + q[n]) -> global ----
    float qv[8], vv[8];
    #pragma unroll
    for (int j = 0; j < 8; ++j) {
        int n = j * 16 + lane15;
        qv[j] = qbuf[b * ATT_ + n];
        vv[j] = vw[n];
    }
    #pragma unroll
    for (int i = 0; i < 2; ++i)
        #pragma unroll
        for (int r = 0; r < 4; ++r) {
            float s = 0.f;
            #pragma unroll
            for (int j = 0; j < 8; ++j)
                s += vv[j] * tanhf(acc[i][j][r] + qv[j]);
            #pragma unroll
            for (int m = 8; m >= 1; m >>= 1) s += __shfl_xor(s, m, 64);
            if (lane15 == 0)
                energies[b * T_ + t0 + w * 32 + i * 16 + quad * 4 + r] = s;
        }
}

// ---------------------------------------------------------------------------
// K3: softmax over T per b (R3-verified); zeroes ctx region for K4 atomics.
// ---------------------------------------------------------------------------
__global__ __launch_bounds__(256) void softmax_kernel(
    const float* __restrict__ energies, const unsigned char* __restrict__ mask,
    float* __restrict__ out)
{
    int b = blockIdx.x, tid = threadIdx.x;
    float* ctx  = out;                 // B*ENC
    float* wout = out + B_ * ENC_;     // B*T

    for (int i = tid; i < ENC_; i += 256) ctx[b * ENC_ + i] = 0.f;

    float e[8];
    float mx = -INFINITY;
    #pragma unroll
    for (int p = 0; p < 8; ++p) {
        int t = p * 256 + tid;
        float v = energies[b * T_ + t];
        if (mask[b * T_ + t]) v = -INFINITY;
        e[p] = v;
        mx = fmaxf(mx, v);
    }
    #pragma unroll
    for (int m = 32; m >= 1; m >>= 1) mx = fmaxf(mx, __shfl_xor(mx, m, 64));
    __shared__ float red[8];
    int wave = tid >> 6;
    if ((tid & 63) == 0) red[wave] = mx;
    __syncthreads();
    mx = fmaxf(fmaxf(red[0], red[1]), fmaxf(red[2], red[3]));

    float sum = 0.f;
    #pragma unroll
    for (int p = 0; p < 8; ++p) {
        e[p] = expf(e[p] - mx);
        sum += e[p];
    }
    #pragma unroll
    for (int m = 32; m >= 1; m >>= 1) sum += __shfl_xor(sum, m, 64);
    if ((tid & 63) == 0) red[4 + wave] = sum;
    __syncthreads();
    sum = red[4] + red[5] + red[6] + red[7];
    float inv = 1.f / sum;
    #pragma unroll
    for (int p = 0; p < 8; ++p)
        wout[b * T_ + p * 256 + tid] = e[p] * inv;
}

// ---------------------------------------------------------------------------
// K4: context[b,e] = sum_t w[b,t]*values[b,t,e].  2048 blocks (8/CU),
// 64-t segment per block, float4-coalesced, atomicAdd into zeroed ctx.
// ---------------------------------------------------------------------------
__global__ __launch_bounds__(256) void context_kernel(
    const float* __restrict__ values, const float* __restrict__ w,
    float* __restrict__ ctx)
{
    int bx = blockIdx.x;
    int b = bx >> 5, seg = bx & 31;
    int tid = threadIdx.x;
    int tt = tid >> 7;                 // 0..1
    int e4 = (tid & 127) * 4;

    __shared__ float sw[64];
    if (tid < 64) sw[tid] = w[b * T_ + seg * 64 + tid];
    __syncthreads();

    const float* vp = values + ((size_t)b * T_ + seg * 64) * ENC_ + e4;
    float4 acc = make_float4(0.f, 0.f, 0.f, 0.f);
    #pragma unroll 8
    for (int t = tt * 32; t < tt * 32 + 32; ++t) {
        float4 v = *(const float4*)(vp + (size_t)t * ENC_);
        float wv = sw[t];
        acc.x += wv * v.x; acc.y += wv * v.y;
        acc.z += wv * v.z; acc.w += wv * v.w;
    }

    __shared__ float red[512];
    if (tt == 1) *(float4*)&red[e4] = acc;
    __syncthreads();
    if (tt == 0) {
        float4 o = *(const float4*)&red[e4];
        atomicAdd(&ctx[b * ENC_ + e4 + 0], acc.x + o.x);
        atomicAdd(&ctx[b * ENC_ + e4 + 1], acc.y + o.y);
        atomicAdd(&ctx[b * ENC_ + e4 + 2], acc.z + o.z);
        atomicAdd(&ctx[b * ENC_ + e4 + 3], acc.w + o.w);
    }
}

// ---------------------------------------------------------------------------
extern "C" void kernel_launch(void* const* d_in, const int* in_sizes, int n_in,
                              void* d_out, int out_size, void* d_ws, size_t ws_size,
                              hipStream_t stream) {
    const float* query        = (const float*)d_in[0];
    const float* values       = (const float*)d_in[1];
    const float* cum          = (const float*)d_in[2];
    const unsigned char* mask = (const unsigned char*)d_in[3];
    const float* Q_w          = (const float*)d_in[4];
    const float* Q_b          = (const float*)d_in[5];
    const float* V_w          = (const float*)d_in[6];
    const float* conv_w       = (const float*)d_in[7];
    const float* loc_proj_w   = (const float*)d_in[8];
    const float* v_w          = (const float*)d_in[9];

    float* out = (float*)d_out;
    char*  ws  = (char*)d_ws;
    // ws layout (bytes) — total 835584 B, same footprint proven in R1-R3:
    //  qbuf @0 (32 KB) | Bph @32768 (128 KB) | Bpl @163840 (128 KB)
    //  effh @294912 (8 KB) | effl @303104 (8 KB) | energies @311296 (512 KB)
    float*          qbuf     = (float*)(ws);
    unsigned short* Bph      = (unsigned short*)(ws + 32768);
    unsigned short* Bpl      = (unsigned short*)(ws + 163840);
    unsigned short* effh     = (unsigned short*)(ws + 294912);
    unsigned short* effl     = (unsigned short*)(ws + 303104);
    float*          energies = (float*)(ws + 311296);

    prep_kernel<<<289, 256, 0, stream>>>(query, Q_w, Q_b, conv_w, loc_proj_w, V_w,
                                         qbuf, Bph, Bpl, effh, effl);
    energy_kernel<<<1024, 256, 0, stream>>>(values, cum, qbuf, Bph, Bpl,
                                            effh, effl, v_w, energies);
    softmax_kernel<<<B_, 256, 0, stream>>>(energies, mask, out);
    context_kernel<<<B_ * 32, 256, 0, stream>>>(values, out + B_ * ENC_, out);
}